// Round 1
// baseline (3453.041 us; speedup 1.0000x reference)
//
#include <hip/hip_runtime.h>
#include <hip/hip_bf16.h>
#include <cstddef>

#define NN 100000
#define EE 1600000
#define CC 1000
#define D0 320   // 2*128+64
#define NH 128

// ---------------- init: deg=1, sums=0, cnt=0 ----------------
__global__ void k_init(float* __restrict__ deg, float* __restrict__ s1,
                       float* __restrict__ s2, float* __restrict__ cnt) {
    int i = blockIdx.x * 256 + threadIdx.x;   // grid covers 128000
    if (i < NN) deg[i] = 1.0f;
    if (i < CC * 128) { s1[i] = 0.f; s2[i] = 0.f; }
    if (i < CC) cnt[i] = 0.f;
}

// ---------------- degree count ----------------
__global__ void k_count(const int* __restrict__ dst, float* __restrict__ deg) {
    int i = blockIdx.x * 256 + threadIdx.x;
    if (i < EE) atomicAdd(&deg[dst[i]], 1.0f);
}

// ---------------- dis = rsqrt(deg) in place ----------------
__global__ void k_dis(float* __restrict__ deg) {
    int i = blockIdx.x * 256 + threadIdx.x;
    if (i < NN) deg[i] = rsqrtf(deg[i]);
}

// ---------------- embed: h0 = [relu(x[:, :7]W1+b1) | relu(x[:,7:]W2+b2) | id] ----------------
__global__ __launch_bounds__(256) void k_embed(
    const float* __restrict__ x, const float* __restrict__ id_emb,
    const float* __restrict__ W1, const float* __restrict__ b1,
    const float* __restrict__ W2, const float* __restrict__ b2,
    float* __restrict__ h0) {
    __shared__ float W1s[7 * 128];
    __shared__ float W2s[12 * 128];
    __shared__ float b1s[128], b2s[128];
    __shared__ float xs[4][20];
    int t = threadIdx.x;
    for (int i = t; i < 7 * 128; i += 256) W1s[i] = W1[i];
    for (int i = t; i < 12 * 128; i += 256) W2s[i] = W2[i];
    if (t < 128) { b1s[t] = b1[t]; b2s[t] = b2[t]; }
    int ln = t >> 6, lane = t & 63;
    int node = blockIdx.x * 4 + ln;
    if (node < NN && lane < 19) xs[ln][lane] = x[(size_t)node * 19 + lane];
    __syncthreads();
    if (node >= NN) return;
    #pragma unroll
    for (int c5 = 0; c5 < 5; ++c5) {
        int c = lane + 64 * c5;
        float v;
        if (c < 128) {
            float acc = b1s[c];
            #pragma unroll
            for (int k = 0; k < 7; ++k) acc += xs[ln][k] * W1s[k * 128 + c];
            v = fmaxf(acc, 0.f);
        } else if (c < 256) {
            int cc = c - 128;
            float acc = b2s[cc];
            #pragma unroll
            for (int k = 0; k < 12; ++k) acc += xs[ln][7 + k] * W2s[k * 128 + cc];
            v = fmaxf(acc, 0.f);
        } else {
            v = id_emb[(size_t)node * 64 + (c - 256)];
        }
        h0[(size_t)node * 320 + c] = v;
    }
}

// ---------------- tiled fp32 GEMM: C = [relu](A@B [+ bias]) ----------------
// A [M,K] row-major, B [K,Nc] row-major. BM=BN=64, BK=32, 256 thr, 4x4 micro.
template <int K, int RELU>
__global__ __launch_bounds__(256) void k_gemm(
    const float* __restrict__ A, const float* __restrict__ B,
    const float* __restrict__ bias, float* __restrict__ Cout,
    int M, int Nc) {
    __shared__ __align__(16) float As[32][68];  // [k][m]
    __shared__ __align__(16) float Bs[32][68];  // [k][n]
    int t = threadIdx.x;
    int rowBase = blockIdx.x * 64;
    int colBase = blockIdx.y * 64;
    int tx = t & 15, ty = t >> 4;
    float acc[4][4] = {};
    for (int kb = 0; kb < K; kb += 32) {
        #pragma unroll
        for (int i = 0; i < 2; ++i) {
            int idx = t + 256 * i;
            int r = idx >> 3;
            int kc = (idx & 7) * 4;
            int grow = rowBase + r;
            float4 v = make_float4(0.f, 0.f, 0.f, 0.f);
            if (grow < M) v = *(const float4*)(A + (size_t)grow * K + kb + kc);
            As[kc + 0][r] = v.x; As[kc + 1][r] = v.y;
            As[kc + 2][r] = v.z; As[kc + 3][r] = v.w;
        }
        #pragma unroll
        for (int i = 0; i < 2; ++i) {
            int idx = t + 256 * i;
            int kr = idx >> 4;
            int c = (idx & 15) * 4;
            *(float4*)(&Bs[kr][c]) = *(const float4*)(B + (size_t)(kb + kr) * Nc + colBase + c);
        }
        __syncthreads();
        #pragma unroll
        for (int k = 0; k < 32; ++k) {
            float4 a4 = *(const float4*)(&As[k][ty * 4]);
            float4 b4 = *(const float4*)(&Bs[k][tx * 4]);
            float av[4] = {a4.x, a4.y, a4.z, a4.w};
            float bv[4] = {b4.x, b4.y, b4.z, b4.w};
            #pragma unroll
            for (int i = 0; i < 4; ++i)
                #pragma unroll
                for (int j = 0; j < 4; ++j)
                    acc[i][j] += av[i] * bv[j];
        }
        __syncthreads();
    }
    #pragma unroll
    for (int i = 0; i < 4; ++i) {
        int grow = rowBase + ty * 4 + i;
        if (grow < M) {
            int gc = colBase + tx * 4;
            float4 o = make_float4(acc[i][0], acc[i][1], acc[i][2], acc[i][3]);
            if (RELU) {
                o.x = fmaxf(o.x + bias[gc + 0], 0.f);
                o.y = fmaxf(o.y + bias[gc + 1], 0.f);
                o.z = fmaxf(o.z + bias[gc + 2], 0.f);
                o.w = fmaxf(o.w + bias[gc + 3], 0.f);
            }
            *(float4*)(Cout + (size_t)grow * Nc + gc) = o;
        }
    }
}

// ---------------- agg init: agg = hw * dis^2 + b ----------------
__global__ void k_selfinit(const float* __restrict__ hw, const float* __restrict__ dis,
                           const float* __restrict__ b, float* __restrict__ agg) {
    int t = blockIdx.x * 256 + threadIdx.x;  // over N*32
    if (t >= NN * 32) return;
    int node = t >> 5, c4 = (t & 31) * 4;
    float ds = dis[node]; ds = ds * ds;
    float4 v = *(const float4*)(hw + (size_t)node * 128 + c4);
    float4 bb = *(const float4*)(b + c4);
    float4 o = make_float4(v.x * ds + bb.x, v.y * ds + bb.y,
                           v.z * ds + bb.z, v.w * ds + bb.w);
    *(float4*)(agg + (size_t)node * 128 + c4) = o;
}

// ---------------- edge scatter: agg[dst] += hw[src] * dis[src]*dis[dst] ----------------
__global__ __launch_bounds__(256) void k_scatter(
    const int* __restrict__ src, const int* __restrict__ dst,
    const float* __restrict__ dis, const float* __restrict__ hw,
    float* __restrict__ agg) {
    int wid = blockIdx.x * 4 + (threadIdx.x >> 6);
    int lane = threadIdx.x & 63;
    if (wid >= EE) return;
    int s = src[wid], d = dst[wid];
    float norm = dis[s] * dis[d];
    float2 v = *(const float2*)(hw + (size_t)s * 128 + lane * 2);
    atomicAdd(agg + (size_t)d * 128 + lane * 2 + 0, v.x * norm);
    atomicAdd(agg + (size_t)d * 128 + lane * 2 + 1, v.y * norm);
}

// ---------------- relu pass: h = max(agg, 0) ----------------
__global__ void k_relu(const float* __restrict__ in, float* __restrict__ out) {
    int t = blockIdx.x * 256 + threadIdx.x;  // over N*32
    if (t >= NN * 32) return;
    float4 v = *(const float4*)(in + (size_t)t * 4);
    float4 o = make_float4(fmaxf(v.x, 0.f), fmaxf(v.y, 0.f),
                           fmaxf(v.z, 0.f), fmaxf(v.w, 0.f));
    *(float4*)(out + (size_t)t * 4) = o;
}

// ---------------- community pool: sums[comm] += h[node], cnt[comm] += 1 ----------------
__global__ __launch_bounds__(256) void k_pool(
    const float* __restrict__ h, const int* __restrict__ comm,
    float* __restrict__ sums, float* __restrict__ cnt, int doCnt) {
    int wid = blockIdx.x * 4 + (threadIdx.x >> 6);
    int lane = threadIdx.x & 63;
    if (wid >= NN) return;
    int cm = comm[wid];
    float2 v = *(const float2*)(h + (size_t)wid * 128 + lane * 2);
    atomicAdd(sums + (size_t)cm * 128 + lane * 2 + 0, v.x);
    atomicAdd(sums + (size_t)cm * 128 + lane * 2 + 1, v.y);
    if (doCnt && lane == 0) atomicAdd(cnt + cm, 1.0f);
}

// ---------------- final MLP over communities ----------------
__global__ __launch_bounds__(128) void k_final(
    const float* __restrict__ s1, const float* __restrict__ s2,
    const float* __restrict__ cnt,
    const float* __restrict__ Wl1, const float* __restrict__ bl1,
    const float* __restrict__ Wl2, const float* __restrict__ bl2,
    float* __restrict__ out) {
    __shared__ float zh[128];
    __shared__ float partial[2];
    int c = blockIdx.x, t = threadIdx.x;
    float invc = 1.0f / fmaxf(cnt[c], 1.0f);
    zh[t] = (s1[(size_t)c * 128 + t] + s2[(size_t)c * 128 + t]) * invc;
    __syncthreads();
    float acc = bl1[t];
    for (int k = 0; k < 128; ++k)
        acc += zh[k] * (Wl1[(size_t)k * 128 + t] + Wl1[(size_t)(k + 128) * 128 + t]);
    float zv = fmaxf(acc, 0.f);
    float p = zv * Wl2[t];
    #pragma unroll
    for (int off = 32; off > 0; off >>= 1) p += __shfl_down(p, off, 64);
    if ((t & 63) == 0) partial[t >> 6] = p;
    __syncthreads();
    if (t == 0) out[c] = partial[0] + partial[1] + bl2[0];
}

extern "C" void kernel_launch(void* const* d_in, const int* in_sizes, int n_in,
                              void* d_out, int out_size, void* d_ws, size_t ws_size,
                              hipStream_t stream) {
    const float* x       = (const float*)d_in[0];
    const int*   edge    = (const int*)d_in[1];
    const int*   comm    = (const int*)d_in[2];
    const float* id_emb  = (const float*)d_in[3];
    const float* W1      = (const float*)d_in[4];
    const float* b1      = (const float*)d_in[5];
    const float* W2      = (const float*)d_in[6];
    const float* b2      = (const float*)d_in[7];
    const float* W3      = (const float*)d_in[8];
    const float* b3      = (const float*)d_in[9];
    const float* Wc1     = (const float*)d_in[10];
    const float* bc1     = (const float*)d_in[11];
    const float* Wc2     = (const float*)d_in[12];
    const float* bc2     = (const float*)d_in[13];
    const float* Wl1     = (const float*)d_in[14];
    const float* bl1     = (const float*)d_in[15];
    const float* Wl2     = (const float*)d_in[16];
    const float* bl2     = (const float*)d_in[17];
    float* out = (float*)d_out;
    float* ws  = (float*)d_ws;

    const int* srcIdx = edge;
    const int* dstIdx = edge + EE;

    size_t o = 0;
    float* dis = ws + o; o += NN;          // deg then rsqrt in-place
    float* cnt = ws + o; o += 1024;
    float* s1  = ws + o; o += (size_t)CC * 128;
    float* s2  = ws + o; o += (size_t)CC * 128;
    o = (o + 1023) & ~(size_t)1023;
    float* bufA = ws + o; o += (size_t)NN * 320;  // h0 -> later hw | agg
    float* bufB = ws + o; o += (size_t)NN * 320;  // h1 -> later h2 -> h3
    float* hw  = bufA;
    float* agg = bufA + (size_t)NN * 128;
    float* h1  = bufB;
    float* h23 = bufB;

    // degree + dis
    k_init<<<500, 256, 0, stream>>>(dis, s1, s2, cnt);
    k_count<<<EE / 256, 256, 0, stream>>>(dstIdx, dis);
    k_dis<<<(NN + 255) / 256, 256, 0, stream>>>(dis);

    // embedding
    k_embed<<<(NN + 3) / 4, 256, 0, stream>>>(x, id_emb, W1, b1, W2, b2, bufA);
    // h1 = relu(h0 @ W3 + b3)
    {
        dim3 g((NN + 63) / 64, 320 / 64);
        k_gemm<320, 1><<<g, 256, 0, stream>>>(bufA, W3, b3, h1, NN, 320);
    }
    // conv1: hw = h1 @ Wc1
    {
        dim3 g((NN + 63) / 64, 128 / 64);
        k_gemm<320, 0><<<g, 256, 0, stream>>>(h1, Wc1, nullptr, hw, NN, 128);
    }
    k_selfinit<<<NN * 32 / 256, 256, 0, stream>>>(hw, dis, bc1, agg);
    k_scatter<<<EE / 4, 256, 0, stream>>>(srcIdx, dstIdx, dis, hw, agg);
    k_relu<<<NN * 32 / 256, 256, 0, stream>>>(agg, h23);   // h2
    k_pool<<<(NN + 3) / 4, 256, 0, stream>>>(h23, comm, s1, cnt, 1);

    // conv2: hw2 = h2 @ Wc2
    {
        dim3 g((NN + 63) / 64, 128 / 64);
        k_gemm<128, 0><<<g, 256, 0, stream>>>(h23, Wc2, nullptr, hw, NN, 128);
    }
    k_selfinit<<<NN * 32 / 256, 256, 0, stream>>>(hw, dis, bc2, agg);
    k_scatter<<<EE / 4, 256, 0, stream>>>(srcIdx, dstIdx, dis, hw, agg);
    k_relu<<<NN * 32 / 256, 256, 0, stream>>>(agg, h23);   // h3
    k_pool<<<(NN + 3) / 4, 256, 0, stream>>>(h23, comm, s2, cnt, 0);

    // final MLP
    k_final<<<CC, 128, 0, stream>>>(s1, s2, cnt, Wl1, bl1, Wl2, bl2, out);
}

// Round 2
// 979.975 us; speedup vs baseline: 3.5236x; 3.5236x over previous
//
#include <hip/hip_runtime.h>
#include <hip/hip_bf16.h>
#include <cstddef>

#define NN 100000
#define EE 1600000
#define CC 1000
#define NB ((NN + 255) / 256)   // 391 scan blocks

// ---------------- init: rowcnt=0, sums=0, cnt=0 ----------------
__global__ void k_init(int* __restrict__ rowcnt, float* __restrict__ s1,
                       float* __restrict__ s2, float* __restrict__ cnt) {
    int i = blockIdx.x * 256 + threadIdx.x;   // grid covers 128000
    if (i < NN) rowcnt[i] = 0;
    if (i < CC * 128) { s1[i] = 0.f; s2[i] = 0.f; }
    if (i < CC) cnt[i] = 0.f;
}

// ---------------- degree histogram over dst ----------------
__global__ void k_counti(const int* __restrict__ dst, int* __restrict__ rowcnt) {
    int i = blockIdx.x * 256 + threadIdx.x;
    if (i < EE) atomicAdd(&rowcnt[dst[i]], 1);
}

// ---------------- dis = rsqrt(deg+1) ----------------
__global__ void k_dis(const int* __restrict__ rowcnt, float* __restrict__ dis) {
    int i = blockIdx.x * 256 + threadIdx.x;
    if (i < NN) dis[i] = rsqrtf((float)rowcnt[i] + 1.0f);
}

// ---------------- scan step 1: per-block sums ----------------
__global__ void k_blocksum(const int* __restrict__ rowcnt, int* __restrict__ bsum) {
    __shared__ int sd[256];
    int t = threadIdx.x, i = blockIdx.x * 256 + t;
    sd[t] = (i < NN) ? rowcnt[i] : 0;
    __syncthreads();
    for (int s = 128; s > 0; s >>= 1) {
        if (t < s) sd[t] += sd[t + s];
        __syncthreads();
    }
    if (t == 0) bsum[blockIdx.x] = sd[0];
}

// ---------------- scan step 2: exclusive scan of block sums (1 block) ----------------
__global__ void k_scanb(int* __restrict__ bsum) {
    __shared__ int sd[512];
    int t = threadIdx.x;
    int v = (t < NB) ? bsum[t] : 0;
    sd[t] = v;
    __syncthreads();
    for (int off = 1; off < 512; off <<= 1) {
        int x = (t >= off) ? sd[t - off] : 0;
        __syncthreads();
        sd[t] += x;
        __syncthreads();
    }
    if (t < NB) bsum[t] = sd[t] - v;   // exclusive
}

// ---------------- scan step 3: write row offsets, zero rowcnt for reuse ----------------
__global__ void k_writeofs(int* __restrict__ rowcnt, const int* __restrict__ bsum,
                           int* __restrict__ rowofs) {
    __shared__ int sd[256];
    int t = threadIdx.x, i = blockIdx.x * 256 + t;
    int v = (i < NN) ? rowcnt[i] : 0;
    sd[t] = v;
    __syncthreads();
    for (int off = 1; off < 256; off <<= 1) {
        int x = (t >= off) ? sd[t - off] : 0;
        __syncthreads();
        sd[t] += x;
        __syncthreads();
    }
    if (i < NN) {
        rowofs[i] = bsum[blockIdx.x] + sd[t] - v;
        rowcnt[i] = 0;                 // reset for fill pass
    }
    if (i == 0) rowofs[NN] = EE;
}

// ---------------- CSR fill: csr_src sorted by dst ----------------
__global__ void k_fill(const int* __restrict__ src, const int* __restrict__ dst,
                       const int* __restrict__ rowofs, int* __restrict__ rowcnt,
                       int* __restrict__ csr_src) {
    int e = blockIdx.x * 256 + threadIdx.x;
    if (e >= EE) return;
    int d = dst[e];
    int pos = rowofs[d] + atomicAdd(&rowcnt[d], 1);
    csr_src[pos] = src[e];
}

// ---------------- embed: h0 = [relu(x[:, :7]W1+b1) | relu(x[:,7:]W2+b2) | id] ----------------
__global__ __launch_bounds__(256) void k_embed(
    const float* __restrict__ x, const float* __restrict__ id_emb,
    const float* __restrict__ W1, const float* __restrict__ b1,
    const float* __restrict__ W2, const float* __restrict__ b2,
    float* __restrict__ h0) {
    __shared__ float W1s[7 * 128];
    __shared__ float W2s[12 * 128];
    __shared__ float b1s[128], b2s[128];
    __shared__ float xs[4][20];
    int t = threadIdx.x;
    for (int i = t; i < 7 * 128; i += 256) W1s[i] = W1[i];
    for (int i = t; i < 12 * 128; i += 256) W2s[i] = W2[i];
    if (t < 128) { b1s[t] = b1[t]; b2s[t] = b2[t]; }
    int ln = t >> 6, lane = t & 63;
    int node = blockIdx.x * 4 + ln;
    if (node < NN && lane < 19) xs[ln][lane] = x[(size_t)node * 19 + lane];
    __syncthreads();
    if (node >= NN) return;
    #pragma unroll
    for (int c5 = 0; c5 < 5; ++c5) {
        int c = lane + 64 * c5;
        float v;
        if (c < 128) {
            float acc = b1s[c];
            #pragma unroll
            for (int k = 0; k < 7; ++k) acc += xs[ln][k] * W1s[k * 128 + c];
            v = fmaxf(acc, 0.f);
        } else if (c < 256) {
            int cc = c - 128;
            float acc = b2s[cc];
            #pragma unroll
            for (int k = 0; k < 12; ++k) acc += xs[ln][7 + k] * W2s[k * 128 + cc];
            v = fmaxf(acc, 0.f);
        } else {
            v = id_emb[(size_t)node * 64 + (c - 256)];
        }
        h0[(size_t)node * 320 + c] = v;
    }
}

// ---------------- tiled fp32 GEMM: C = [relu](A@B [+ bias]) ----------------
template <int K, int RELU>
__global__ __launch_bounds__(256) void k_gemm(
    const float* __restrict__ A, const float* __restrict__ B,
    const float* __restrict__ bias, float* __restrict__ Cout,
    int M, int Nc) {
    __shared__ __align__(16) float As[32][68];  // [k][m]
    __shared__ __align__(16) float Bs[32][68];  // [k][n]
    int t = threadIdx.x;
    int rowBase = blockIdx.x * 64;
    int colBase = blockIdx.y * 64;
    int tx = t & 15, ty = t >> 4;
    float acc[4][4] = {};
    for (int kb = 0; kb < K; kb += 32) {
        #pragma unroll
        for (int i = 0; i < 2; ++i) {
            int idx = t + 256 * i;
            int r = idx >> 3;
            int kc = (idx & 7) * 4;
            int grow = rowBase + r;
            float4 v = make_float4(0.f, 0.f, 0.f, 0.f);
            if (grow < M) v = *(const float4*)(A + (size_t)grow * K + kb + kc);
            As[kc + 0][r] = v.x; As[kc + 1][r] = v.y;
            As[kc + 2][r] = v.z; As[kc + 3][r] = v.w;
        }
        #pragma unroll
        for (int i = 0; i < 2; ++i) {
            int idx = t + 256 * i;
            int kr = idx >> 4;
            int c = (idx & 15) * 4;
            *(float4*)(&Bs[kr][c]) = *(const float4*)(B + (size_t)(kb + kr) * Nc + colBase + c);
        }
        __syncthreads();
        #pragma unroll
        for (int k = 0; k < 32; ++k) {
            float4 a4 = *(const float4*)(&As[k][ty * 4]);
            float4 b4 = *(const float4*)(&Bs[k][tx * 4]);
            float av[4] = {a4.x, a4.y, a4.z, a4.w};
            float bv[4] = {b4.x, b4.y, b4.z, b4.w};
            #pragma unroll
            for (int i = 0; i < 4; ++i)
                #pragma unroll
                for (int j = 0; j < 4; ++j)
                    acc[i][j] += av[i] * bv[j];
        }
        __syncthreads();
    }
    #pragma unroll
    for (int i = 0; i < 4; ++i) {
        int grow = rowBase + ty * 4 + i;
        if (grow < M) {
            int gc = colBase + tx * 4;
            float4 o = make_float4(acc[i][0], acc[i][1], acc[i][2], acc[i][3]);
            if (RELU) {
                o.x = fmaxf(o.x + bias[gc + 0], 0.f);
                o.y = fmaxf(o.y + bias[gc + 1], 0.f);
                o.z = fmaxf(o.z + bias[gc + 2], 0.f);
                o.w = fmaxf(o.w + bias[gc + 3], 0.f);
            }
            *(float4*)(Cout + (size_t)grow * Nc + gc) = o;
        }
    }
}

// ---------------- fused gather conv: h = relu(sum_{e} hw[src]*norm + hw*dis^2 + b)
//                  + community-pool atomics ----------------
__global__ __launch_bounds__(256) void k_gather(
    const int* __restrict__ rowofs, const int* __restrict__ csr_src,
    const float* __restrict__ dis, const float* __restrict__ hw,
    const float* __restrict__ bias, const int* __restrict__ comm,
    float* __restrict__ hout, float* __restrict__ sums,
    float* __restrict__ cnt, int doCnt) {
    int wid = blockIdx.x * 4 + (threadIdx.x >> 6);
    int lane = threadIdx.x & 63;
    if (wid >= NN) return;
    int ro = rowofs[wid], re = rowofs[wid + 1];
    int c = lane * 2;
    float dsd = dis[wid];
    float self = dsd * dsd;
    float2 hv = *(const float2*)(hw + (size_t)wid * 128 + c);
    float a0 = hv.x * self + bias[c];
    float a1 = hv.y * self + bias[c + 1];
    int e = ro;
    for (; e + 1 < re; e += 2) {
        int s0 = csr_src[e], s1 = csr_src[e + 1];
        float n0 = dis[s0] * dsd, n1 = dis[s1] * dsd;
        float2 v0 = *(const float2*)(hw + (size_t)s0 * 128 + c);
        float2 v1 = *(const float2*)(hw + (size_t)s1 * 128 + c);
        a0 += v0.x * n0 + v1.x * n1;
        a1 += v0.y * n0 + v1.y * n1;
    }
    if (e < re) {
        int s0 = csr_src[e];
        float n0 = dis[s0] * dsd;
        float2 v0 = *(const float2*)(hw + (size_t)s0 * 128 + c);
        a0 += v0.x * n0;
        a1 += v0.y * n0;
    }
    a0 = fmaxf(a0, 0.f);
    a1 = fmaxf(a1, 0.f);
    *(float2*)(hout + (size_t)wid * 128 + c) = make_float2(a0, a1);
    int cm = comm[wid];
    atomicAdd(sums + (size_t)cm * 128 + c + 0, a0);
    atomicAdd(sums + (size_t)cm * 128 + c + 1, a1);
    if (doCnt && lane == 0) atomicAdd(cnt + cm, 1.0f);
}

// ---------------- final MLP over communities ----------------
__global__ __launch_bounds__(128) void k_final(
    const float* __restrict__ s1, const float* __restrict__ s2,
    const float* __restrict__ cnt,
    const float* __restrict__ Wl1, const float* __restrict__ bl1,
    const float* __restrict__ Wl2, const float* __restrict__ bl2,
    float* __restrict__ out) {
    __shared__ float zh[128];
    __shared__ float partial[2];
    int c = blockIdx.x, t = threadIdx.x;
    float invc = 1.0f / fmaxf(cnt[c], 1.0f);
    zh[t] = (s1[(size_t)c * 128 + t] + s2[(size_t)c * 128 + t]) * invc;
    __syncthreads();
    float acc = bl1[t];
    for (int k = 0; k < 128; ++k)
        acc += zh[k] * (Wl1[(size_t)k * 128 + t] + Wl1[(size_t)(k + 128) * 128 + t]);
    float zv = fmaxf(acc, 0.f);
    float p = zv * Wl2[t];
    #pragma unroll
    for (int off = 32; off > 0; off >>= 1) p += __shfl_down(p, off, 64);
    if ((t & 63) == 0) partial[t >> 6] = p;
    __syncthreads();
    if (t == 0) out[c] = partial[0] + partial[1] + bl2[0];
}

extern "C" void kernel_launch(void* const* d_in, const int* in_sizes, int n_in,
                              void* d_out, int out_size, void* d_ws, size_t ws_size,
                              hipStream_t stream) {
    const float* x       = (const float*)d_in[0];
    const int*   edge    = (const int*)d_in[1];
    const int*   comm    = (const int*)d_in[2];
    const float* id_emb  = (const float*)d_in[3];
    const float* W1      = (const float*)d_in[4];
    const float* b1      = (const float*)d_in[5];
    const float* W2      = (const float*)d_in[6];
    const float* b2      = (const float*)d_in[7];
    const float* W3      = (const float*)d_in[8];
    const float* b3      = (const float*)d_in[9];
    const float* Wc1     = (const float*)d_in[10];
    const float* bc1     = (const float*)d_in[11];
    const float* Wc2     = (const float*)d_in[12];
    const float* bc2     = (const float*)d_in[13];
    const float* Wl1     = (const float*)d_in[14];
    const float* bl1     = (const float*)d_in[15];
    const float* Wl2     = (const float*)d_in[16];
    const float* bl2     = (const float*)d_in[17];
    float* out = (float*)d_out;
    float* ws  = (float*)d_ws;

    const int* srcIdx = edge;
    const int* dstIdx = edge + EE;

    size_t o = 0;
    float* dis  = ws + o; o += NN;
    float* cnt  = ws + o; o += 1024;
    float* s1   = ws + o; o += (size_t)CC * 128;
    float* s2   = ws + o; o += (size_t)CC * 128;
    int* rowcnt = (int*)(ws + o); o += NN;
    int* rowofs = (int*)(ws + o); o += NN + 8;
    int* bsum   = (int*)(ws + o); o += 512;
    int* csrsrc = (int*)(ws + o); o += EE;
    o = (o + 1023) & ~(size_t)1023;
    float* bufA = ws + o; o += (size_t)NN * 320;  // h0, later hw
    float* bufB = ws + o; o += (size_t)NN * 320;  // h1, later h2/h3
    float* hw = bufA;
    float* h1 = bufB;
    float* h23 = bufB;

    // ---- CSR build + degree norm ----
    k_init<<<500, 256, 0, stream>>>(rowcnt, s1, s2, cnt);
    k_counti<<<EE / 256, 256, 0, stream>>>(dstIdx, rowcnt);
    k_dis<<<(NN + 255) / 256, 256, 0, stream>>>(rowcnt, dis);
    k_blocksum<<<NB, 256, 0, stream>>>(rowcnt, bsum);
    k_scanb<<<1, 512, 0, stream>>>(bsum);
    k_writeofs<<<NB, 256, 0, stream>>>(rowcnt, bsum, rowofs);
    k_fill<<<EE / 256, 256, 0, stream>>>(srcIdx, dstIdx, rowofs, rowcnt, csrsrc);

    // ---- embedding ----
    k_embed<<<(NN + 3) / 4, 256, 0, stream>>>(x, id_emb, W1, b1, W2, b2, bufA);
    {   // h1 = relu(h0 @ W3 + b3)
        dim3 g((NN + 63) / 64, 320 / 64);
        k_gemm<320, 1><<<g, 256, 0, stream>>>(bufA, W3, b3, h1, NN, 320);
    }
    // ---- conv1 ----
    {
        dim3 g((NN + 63) / 64, 128 / 64);
        k_gemm<320, 0><<<g, 256, 0, stream>>>(h1, Wc1, nullptr, hw, NN, 128);
    }
    k_gather<<<(NN + 3) / 4, 256, 0, stream>>>(rowofs, csrsrc, dis, hw, bc1, comm,
                                               h23, s1, cnt, 1);
    // ---- conv2 ----
    {
        dim3 g((NN + 63) / 64, 128 / 64);
        k_gemm<128, 0><<<g, 256, 0, stream>>>(h23, Wc2, nullptr, hw, NN, 128);
    }
    k_gather<<<(NN + 3) / 4, 256, 0, stream>>>(rowofs, csrsrc, dis, hw, bc2, comm,
                                               h23, s2, cnt, 0);

    // ---- final MLP ----
    k_final<<<CC, 128, 0, stream>>>(s1, s2, cnt, Wl1, bl1, Wl2, bl2, out);
}

// Round 3
// 704.257 us; speedup vs baseline: 4.9031x; 1.3915x over previous
//
#include <hip/hip_runtime.h>
#include <hip/hip_bf16.h>
#include <cstddef>

#define NN 100000
#define EE 1600000
#define CC 1000
#define NB ((NN + 255) / 256)   // 391 scan blocks

using short8 = __attribute__((ext_vector_type(8))) short;
using f32x4  = __attribute__((ext_vector_type(4))) float;

__device__ __forceinline__ float bf2f(unsigned int u) {
    union { unsigned int i; float f; } x; x.i = u << 16; return x.f;
}
__device__ __forceinline__ unsigned short f2bf(float f) {
    __hip_bfloat16 h = __float2bfloat16(f);
    return *reinterpret_cast<unsigned short*>(&h);
}

// ---------------- init: rowcnt=0, sums=0, cnt=0 ----------------
__global__ void k_init(int* __restrict__ rowcnt, float* __restrict__ s1,
                       float* __restrict__ s2, float* __restrict__ cnt) {
    int i = blockIdx.x * 256 + threadIdx.x;   // grid covers 128000
    if (i < NN) rowcnt[i] = 0;
    if (i < CC * 128) { s1[i] = 0.f; s2[i] = 0.f; }
    if (i < CC) cnt[i] = 0.f;
}

// ---------------- degree histogram over dst ----------------
__global__ void k_counti(const int* __restrict__ dst, int* __restrict__ rowcnt) {
    int i = blockIdx.x * 256 + threadIdx.x;
    if (i < EE) atomicAdd(&rowcnt[dst[i]], 1);
}

// ---------------- dis = rsqrt(deg+1) ----------------
__global__ void k_dis(const int* __restrict__ rowcnt, float* __restrict__ dis) {
    int i = blockIdx.x * 256 + threadIdx.x;
    if (i < NN) dis[i] = rsqrtf((float)rowcnt[i] + 1.0f);
}

// ---------------- scan step 1: per-block sums ----------------
__global__ void k_blocksum(const int* __restrict__ rowcnt, int* __restrict__ bsum) {
    __shared__ int sd[256];
    int t = threadIdx.x, i = blockIdx.x * 256 + t;
    sd[t] = (i < NN) ? rowcnt[i] : 0;
    __syncthreads();
    for (int s = 128; s > 0; s >>= 1) {
        if (t < s) sd[t] += sd[t + s];
        __syncthreads();
    }
    if (t == 0) bsum[blockIdx.x] = sd[0];
}

// ---------------- scan step 2: exclusive scan of block sums (1 block) ----------------
__global__ void k_scanb(int* __restrict__ bsum) {
    __shared__ int sd[512];
    int t = threadIdx.x;
    int v = (t < NB) ? bsum[t] : 0;
    sd[t] = v;
    __syncthreads();
    for (int off = 1; off < 512; off <<= 1) {
        int x = (t >= off) ? sd[t - off] : 0;
        __syncthreads();
        sd[t] += x;
        __syncthreads();
    }
    if (t < NB) bsum[t] = sd[t] - v;   // exclusive
}

// ---------------- scan step 3: write row offsets, zero rowcnt for reuse ----------------
__global__ void k_writeofs(int* __restrict__ rowcnt, const int* __restrict__ bsum,
                           int* __restrict__ rowofs) {
    __shared__ int sd[256];
    int t = threadIdx.x, i = blockIdx.x * 256 + t;
    int v = (i < NN) ? rowcnt[i] : 0;
    sd[t] = v;
    __syncthreads();
    for (int off = 1; off < 256; off <<= 1) {
        int x = (t >= off) ? sd[t - off] : 0;
        __syncthreads();
        sd[t] += x;
        __syncthreads();
    }
    if (i < NN) {
        rowofs[i] = bsum[blockIdx.x] + sd[t] - v;
        rowcnt[i] = 0;                 // reset for fill pass
    }
    if (i == 0) rowofs[NN] = EE;
}

// ---------------- CSR fill: csr_src sorted by dst ----------------
__global__ void k_fill(const int* __restrict__ src, const int* __restrict__ dst,
                       const int* __restrict__ rowofs, int* __restrict__ rowcnt,
                       int* __restrict__ csr_src) {
    int e = blockIdx.x * 256 + threadIdx.x;
    if (e >= EE) return;
    int d = dst[e];
    int pos = rowofs[d] + atomicAdd(&rowcnt[d], 1);
    csr_src[pos] = src[e];
}

// ---------------- weight convert+transpose: W[K][N] f32 -> Wt[N][K+8] bf16 ----------------
__global__ void k_wconv(const float* __restrict__ W, unsigned short* __restrict__ Wt,
                        int K, int N) {
    int n = blockIdx.y;
    int k = blockIdx.x * 256 + threadIdx.x;
    if (k >= K + 8) return;
    unsigned short v = 0;
    if (k < K) v = f2bf(W[(size_t)k * N + n]);
    Wt[(size_t)n * (K + 8) + k] = v;
}

// ---------------- embed: h0 = [relu(x[:, :7]W1+b1) | relu(x[:,7:]W2+b2) | id], bf16 ----------------
__global__ __launch_bounds__(256) void k_embed(
    const float* __restrict__ x, const float* __restrict__ id_emb,
    const float* __restrict__ W1, const float* __restrict__ b1,
    const float* __restrict__ W2, const float* __restrict__ b2,
    unsigned short* __restrict__ h0) {
    __shared__ float W1s[7 * 128];
    __shared__ float W2s[12 * 128];
    __shared__ float b1s[128], b2s[128];
    __shared__ float xs[4][20];
    int t = threadIdx.x;
    for (int i = t; i < 7 * 128; i += 256) W1s[i] = W1[i];
    for (int i = t; i < 12 * 128; i += 256) W2s[i] = W2[i];
    if (t < 128) { b1s[t] = b1[t]; b2s[t] = b2[t]; }
    int ln = t >> 6, lane = t & 63;
    int node = blockIdx.x * 4 + ln;
    if (node < NN && lane < 19) xs[ln][lane] = x[(size_t)node * 19 + lane];
    __syncthreads();
    if (node >= NN) return;
    #pragma unroll
    for (int c5 = 0; c5 < 5; ++c5) {
        int c = lane + 64 * c5;
        float v;
        if (c < 128) {
            float acc = b1s[c];
            #pragma unroll
            for (int k = 0; k < 7; ++k) acc += xs[ln][k] * W1s[k * 128 + c];
            v = fmaxf(acc, 0.f);
        } else if (c < 256) {
            int cc = c - 128;
            float acc = b2s[cc];
            #pragma unroll
            for (int k = 0; k < 12; ++k) acc += xs[ln][7 + k] * W2s[k * 128 + cc];
            v = fmaxf(acc, 0.f);
        } else {
            v = id_emb[(size_t)node * 64 + (c - 256)];
        }
        h0[(size_t)node * 320 + c] = f2bf(v);
    }
}

// ---------------- bf16 MFMA GEMM: C = [relu](A@B [+bias]), A[M,K] bf16, Bt[N][K+8] bf16 ----------------
// 128x64 tile, 4 waves (2x2), wave tile 64x32 = 4x2 frags of 16x16, fp32 acc.
template <int K, int N, int RELU>
__global__ __launch_bounds__(256) void k_mgemm(
    const unsigned short* __restrict__ A, const unsigned short* __restrict__ Bt,
    const float* __restrict__ bias, unsigned short* __restrict__ C, int M) {
    __shared__ short As[128][40];        // BK=32, +8 pad (80B row, 16B-aligned)
    __shared__ short Bs[64][K + 8];
    constexpr int CH = (K + 8) / 8;
    int t = threadIdx.x;
    int rowBase = blockIdx.x * 128;
    int colBase = blockIdx.y * 64;
    // stage Bt panel once
    for (int idx = t; idx < 64 * CH; idx += 256) {
        int r = idx / CH, c = idx % CH;
        *(short8*)&Bs[r][c * 8] =
            *(const short8*)(Bt + (size_t)(colBase + r) * (K + 8) + c * 8);
    }
    int wid = t >> 6, lane = t & 63;
    int wm = wid >> 1, wn = wid & 1;
    int fr = lane & 15, g = lane >> 4;
    f32x4 acc[4][2] = {};
    for (int kb = 0; kb < K; kb += 32) {
        __syncthreads();     // As reuse guard (also covers initial Bs stage)
        #pragma unroll
        for (int p = 0; p < 2; ++p) {
            int ci = t + 256 * p;
            int r = ci >> 2, q = ci & 3;
            int grow = rowBase + r;
            short8 v = {};
            if (grow < M) v = *(const short8*)(A + (size_t)grow * K + kb + q * 8);
            *(short8*)&As[r][q * 8] = v;
        }
        __syncthreads();
        short8 b0 = *(const short8*)&Bs[wn * 32 + fr][kb + g * 8];
        short8 b1 = *(const short8*)&Bs[wn * 32 + 16 + fr][kb + g * 8];
        #pragma unroll
        for (int mf = 0; mf < 4; ++mf) {
            short8 a = *(const short8*)&As[wm * 64 + mf * 16 + fr][g * 8];
            acc[mf][0] = __builtin_amdgcn_mfma_f32_16x16x32_bf16(a, b0, acc[mf][0], 0, 0, 0);
            acc[mf][1] = __builtin_amdgcn_mfma_f32_16x16x32_bf16(a, b1, acc[mf][1], 0, 0, 0);
        }
    }
    // epilogue: C/D layout col=lane&15, row=(lane>>4)*4+reg
    #pragma unroll
    for (int nf = 0; nf < 2; ++nf) {
        int col = colBase + wn * 32 + nf * 16 + fr;
        float bv = RELU ? bias[col] : 0.f;
        #pragma unroll
        for (int mf = 0; mf < 4; ++mf) {
            #pragma unroll
            for (int r = 0; r < 4; ++r) {
                int row = rowBase + wm * 64 + mf * 16 + g * 4 + r;
                if (row < M) {
                    float v = acc[mf][nf][r];
                    if (RELU) v = fmaxf(v + bv, 0.f);
                    C[(size_t)row * N + col] = f2bf(v);
                }
            }
        }
    }
}

// ---------------- fused gather conv (bf16 in/out): h = relu(sum hw[src]*norm + hw*dis^2 + b)
//                  + community-pool atomics ----------------
__global__ __launch_bounds__(256) void k_gather(
    const int* __restrict__ rowofs, const int* __restrict__ csr_src,
    const float* __restrict__ dis, const unsigned short* __restrict__ hw,
    const float* __restrict__ bias, const int* __restrict__ comm,
    unsigned short* __restrict__ hout, float* __restrict__ sums,
    float* __restrict__ cnt, int doCnt) {
    int wid = blockIdx.x * 4 + (threadIdx.x >> 6);
    int lane = threadIdx.x & 63;
    if (wid >= NN) return;
    int ro = rowofs[wid], re = rowofs[wid + 1];
    int c = lane * 2;
    float dsd = dis[wid];
    float self = dsd * dsd;
    unsigned int hv = *(const unsigned int*)(hw + (size_t)wid * 128 + c);
    float a0 = bf2f(hv & 0xffffu) * self + bias[c];
    float a1 = bf2f(hv >> 16) * self + bias[c + 1];
    int e = ro;
    for (; e + 1 < re; e += 2) {
        int s0 = csr_src[e], s1i = csr_src[e + 1];
        float n0 = dis[s0] * dsd, n1 = dis[s1i] * dsd;
        unsigned int v0 = *(const unsigned int*)(hw + (size_t)s0 * 128 + c);
        unsigned int v1 = *(const unsigned int*)(hw + (size_t)s1i * 128 + c);
        a0 += bf2f(v0 & 0xffffu) * n0 + bf2f(v1 & 0xffffu) * n1;
        a1 += bf2f(v0 >> 16) * n0 + bf2f(v1 >> 16) * n1;
    }
    if (e < re) {
        int s0 = csr_src[e];
        float n0 = dis[s0] * dsd;
        unsigned int v0 = *(const unsigned int*)(hw + (size_t)s0 * 128 + c);
        a0 += bf2f(v0 & 0xffffu) * n0;
        a1 += bf2f(v0 >> 16) * n0;
    }
    a0 = fmaxf(a0, 0.f);
    a1 = fmaxf(a1, 0.f);
    unsigned int packed = ((unsigned int)f2bf(a1) << 16) | f2bf(a0);
    *(unsigned int*)(hout + (size_t)wid * 128 + c) = packed;
    int cm = comm[wid];
    atomicAdd(sums + (size_t)cm * 128 + c + 0, a0);
    atomicAdd(sums + (size_t)cm * 128 + c + 1, a1);
    if (doCnt && lane == 0) atomicAdd(cnt + cm, 1.0f);
}

// ---------------- final MLP over communities (fp32) ----------------
__global__ __launch_bounds__(128) void k_final(
    const float* __restrict__ s1, const float* __restrict__ s2,
    const float* __restrict__ cnt,
    const float* __restrict__ Wl1, const float* __restrict__ bl1,
    const float* __restrict__ Wl2, const float* __restrict__ bl2,
    float* __restrict__ out) {
    __shared__ float zh[128];
    __shared__ float partial[2];
    int c = blockIdx.x, t = threadIdx.x;
    float invc = 1.0f / fmaxf(cnt[c], 1.0f);
    zh[t] = (s1[(size_t)c * 128 + t] + s2[(size_t)c * 128 + t]) * invc;
    __syncthreads();
    float acc = bl1[t];
    for (int k = 0; k < 128; ++k)
        acc += zh[k] * (Wl1[(size_t)k * 128 + t] + Wl1[(size_t)(k + 128) * 128 + t]);
    float zv = fmaxf(acc, 0.f);
    float p = zv * Wl2[t];
    #pragma unroll
    for (int off = 32; off > 0; off >>= 1) p += __shfl_down(p, off, 64);
    if ((t & 63) == 0) partial[t >> 6] = p;
    __syncthreads();
    if (t == 0) out[c] = partial[0] + partial[1] + bl2[0];
}

extern "C" void kernel_launch(void* const* d_in, const int* in_sizes, int n_in,
                              void* d_out, int out_size, void* d_ws, size_t ws_size,
                              hipStream_t stream) {
    const float* x       = (const float*)d_in[0];
    const int*   edge    = (const int*)d_in[1];
    const int*   comm    = (const int*)d_in[2];
    const float* id_emb  = (const float*)d_in[3];
    const float* W1      = (const float*)d_in[4];
    const float* b1      = (const float*)d_in[5];
    const float* W2      = (const float*)d_in[6];
    const float* b2      = (const float*)d_in[7];
    const float* W3      = (const float*)d_in[8];
    const float* b3      = (const float*)d_in[9];
    const float* Wc1     = (const float*)d_in[10];
    const float* bc1     = (const float*)d_in[11];
    const float* Wc2     = (const float*)d_in[12];
    const float* bc2     = (const float*)d_in[13];
    const float* Wl1     = (const float*)d_in[14];
    const float* bl1     = (const float*)d_in[15];
    const float* Wl2     = (const float*)d_in[16];
    const float* bl2     = (const float*)d_in[17];
    float* out = (float*)d_out;
    float* ws  = (float*)d_ws;

    const int* srcIdx = edge;
    const int* dstIdx = edge + EE;

    size_t o = 0;
    auto alloc = [&](size_t nfloats) {
        float* p = ws + o; o += (nfloats + 3) & ~(size_t)3; return p;
    };
    float* dis  = alloc(NN);
    float* cnt  = alloc(1024);
    float* s1   = alloc((size_t)CC * 128);
    float* s2   = alloc((size_t)CC * 128);
    int* rowcnt = (int*)alloc(NN);
    int* rowofs = (int*)alloc(NN + 8);
    int* bsum   = (int*)alloc(512);
    int* csrsrc = (int*)alloc(EE);
    unsigned short* W3t  = (unsigned short*)alloc(320 * 328 / 2);
    unsigned short* Wc1t = (unsigned short*)alloc(128 * 328 / 2);
    unsigned short* Wc2t = (unsigned short*)alloc(128 * 136 / 2);
    unsigned short* h0   = (unsigned short*)alloc((size_t)NN * 320 / 2);
    unsigned short* h1   = (unsigned short*)alloc((size_t)NN * 320 / 2);
    unsigned short* hwb  = (unsigned short*)alloc((size_t)NN * 128 / 2);
    unsigned short* h23  = (unsigned short*)alloc((size_t)NN * 128 / 2);

    // ---- CSR build + degree norm ----
    k_init<<<500, 256, 0, stream>>>(rowcnt, s1, s2, cnt);
    k_counti<<<EE / 256, 256, 0, stream>>>(dstIdx, rowcnt);
    k_dis<<<(NN + 255) / 256, 256, 0, stream>>>(rowcnt, dis);
    k_blocksum<<<NB, 256, 0, stream>>>(rowcnt, bsum);
    k_scanb<<<1, 512, 0, stream>>>(bsum);
    k_writeofs<<<NB, 256, 0, stream>>>(rowcnt, bsum, rowofs);
    k_fill<<<EE / 256, 256, 0, stream>>>(srcIdx, dstIdx, rowofs, rowcnt, csrsrc);

    // ---- weight convert/transpose to bf16 ----
    k_wconv<<<dim3(2, 320), 256, 0, stream>>>(W3, W3t, 320, 320);
    k_wconv<<<dim3(2, 128), 256, 0, stream>>>(Wc1, Wc1t, 320, 128);
    k_wconv<<<dim3(1, 128), 256, 0, stream>>>(Wc2, Wc2t, 128, 128);

    // ---- embedding (bf16 out) ----
    k_embed<<<(NN + 3) / 4, 256, 0, stream>>>(x, id_emb, W1, b1, W2, b2, h0);

    int rb = (NN + 127) / 128;   // 782
    // h1 = relu(h0 @ W3 + b3)
    k_mgemm<320, 320, 1><<<dim3(rb, 5), 256, 0, stream>>>(h0, W3t, b3, h1, NN);
    // conv1: hw = h1 @ Wc1
    k_mgemm<320, 128, 0><<<dim3(rb, 2), 256, 0, stream>>>(h1, Wc1t, nullptr, hwb, NN);
    k_gather<<<(NN + 3) / 4, 256, 0, stream>>>(rowofs, csrsrc, dis, hwb, bc1, comm,
                                               h23, s1, cnt, 1);
    // conv2: hw = h2 @ Wc2
    k_mgemm<128, 128, 0><<<dim3(rb, 2), 256, 0, stream>>>(h23, Wc2t, nullptr, hwb, NN);
    k_gather<<<(NN + 3) / 4, 256, 0, stream>>>(rowofs, csrsrc, dis, hwb, bc2, comm,
                                               h23, s2, cnt, 0);

    // ---- final MLP ----
    k_final<<<CC, 128, 0, stream>>>(s1, s2, cnt, Wl1, bl1, Wl2, bl2, out);
}